// Round 1
// baseline (195.086 us; speedup 1.0000x reference)
//
#include <hip/hip_runtime.h>
#include <stdint.h>

// Problem constants (B,S,D,O,E) = (16,512,512,512,8)
#define B_ 16
#define S_ 512
#define D_ 512
#define O_ 512
#define E_ 8

typedef unsigned short ushort_t;
typedef __attribute__((ext_vector_type(8))) short short8;
typedef __attribute__((ext_vector_type(8))) unsigned short ushort8;
typedef __attribute__((ext_vector_type(4))) float f32x4;

// round-to-nearest-even f32 -> bf16
__device__ __forceinline__ ushort_t f2bf(float f) {
  union { float f; unsigned int u; } v; v.f = f;
  unsigned int u = v.u;
  return (ushort_t)((u + 0x7fffu + ((u >> 16) & 1u)) >> 16);
}

// async global->LDS, 16B per lane (wave-uniform LDS base + lane*16 pattern)
__device__ __forceinline__ void gld_lds16(const void* g, void* l) {
  __builtin_amdgcn_global_load_lds((__attribute__((address_space(1))) void*)(g),
                                   (__attribute__((address_space(3))) void*)(l),
                                   16, 0, 0);
}

// ---------------- elementwise / prep kernels ----------------

// x (B,S,D) f32 -> bf16, 8 elems/thread
__global__ __launch_bounds__(256) void k_cvt_x(const float* __restrict__ x,
                                               ushort_t* __restrict__ xb) {
  size_t i8 = ((size_t)blockIdx.x * 256 + threadIdx.x) * 8;
  const float4* p = (const float4*)(x + i8);
  float4 a = p[0], b = p[1];
  ushort8 o;
  o[0] = f2bf(a.x); o[1] = f2bf(a.y); o[2] = f2bf(a.z); o[3] = f2bf(a.w);
  o[4] = f2bf(b.x); o[5] = f2bf(b.y); o[6] = f2bf(b.z); o[7] = f2bf(b.w);
  *(ushort8*)(xb + i8) = o;
}

// Wc (E,D,O) f32 -> WcT (E,O,D) bf16 via LDS tile transpose (64x64 tiles)
__global__ __launch_bounds__(256) void k_wcT(const float* __restrict__ Wc,
                                             ushort_t* __restrict__ WcT) {
  __shared__ float tile[64][65];
  const int e = blockIdx.z, d0 = blockIdx.y * 64, o0 = blockIdx.x * 64;
  const float* src = Wc + (size_t)e * D_ * O_;
#pragma unroll
  for (int i = 0; i < 16; ++i) {
    int idx = i * 256 + threadIdx.x;
    int r = idx >> 6, c = idx & 63;
    tile[r][c] = src[(size_t)(d0 + r) * O_ + o0 + c];
  }
  __syncthreads();
  ushort_t* dst = WcT + (size_t)e * O_ * D_;
#pragma unroll
  for (int i = 0; i < 16; ++i) {
    int idx = i * 256 + threadIdx.x;
    int r = idx >> 6, c = idx & 63;  // r: o-row, c: d-col
    dst[(size_t)(o0 + r) * D_ + d0 + c] = f2bf(tile[c][r]);
  }
}

// gates (B,E,S) = sigmoid(x . Wg[e] + bg[e]); one wave per (b,s) row
__global__ __launch_bounds__(256) void k_gates(const float* __restrict__ x,
                                               const float* __restrict__ Wg,
                                               const float* __restrict__ bg,
                                               float* __restrict__ gates) {
  const int wave = threadIdx.x >> 6, lane = threadIdx.x & 63;
  const int row = blockIdx.x * 4 + wave;  // b*S + s
  const float4* xr = (const float4*)(x + (size_t)row * D_);
  float4 x0 = xr[lane], x1 = xr[lane + 64];
  float p[E_];
#pragma unroll
  for (int e = 0; e < E_; ++e) {
    const float4* wr_ = (const float4*)(Wg + e * D_);
    float4 w0 = wr_[lane], w1 = wr_[lane + 64];
    p[e] = x0.x * w0.x + x0.y * w0.y + x0.z * w0.z + x0.w * w0.w +
           x1.x * w1.x + x1.y * w1.y + x1.z * w1.z + x1.w * w1.w;
  }
#pragma unroll
  for (int e = 0; e < E_; ++e) {
    float v = p[e];
#pragma unroll
    for (int off = 32; off > 0; off >>= 1) v += __shfl_xor(v, off, 64);
    p[e] = v;
  }
  const int b = row >> 9, s = row & (S_ - 1);
#pragma unroll
  for (int e = 0; e < E_; ++e)
    if (lane == e) {
      float z = p[e] + bg[e];
      gates[((size_t)(b * E_ + e)) * S_ + s] = 1.f / (1.f + __expf(-z));
    }
}

// Ahat (B,E,S,S) bf16 = adj * gates[b,e,t]  (t = fastest dim)
__global__ __launch_bounds__(256) void k_ahat(const float* __restrict__ adj,
                                              const float* __restrict__ gates,
                                              ushort_t* __restrict__ Ahat) {
  size_t i8 = ((size_t)blockIdx.x * 256 + threadIdx.x) * 8;
  int t8 = (int)(i8 & (S_ - 1));
  size_t be = (i8 >> 9) >> 9;  // b*E + e
  const float4* pa = (const float4*)(adj + i8);
  const float4* pg = (const float4*)(gates + be * S_ + t8);
  float4 a0 = pa[0], a1 = pa[1];
  float4 g0 = pg[0], g1 = pg[1];
  ushort8 o;
  o[0] = f2bf(a0.x * g0.x); o[1] = f2bf(a0.y * g0.y);
  o[2] = f2bf(a0.z * g0.z); o[3] = f2bf(a0.w * g0.w);
  o[4] = f2bf(a1.x * g1.x); o[5] = f2bf(a1.y * g1.y);
  o[6] = f2bf(a1.z * g1.z); o[7] = f2bf(a1.w * g1.w);
  *(ushort8*)(Ahat + i8) = o;
}

// ---------------- GEMM kernels (m97 structure: 128x128 tile, BK=64) ----------------
// 4 waves (2x2), each wave owns 64x64 (4x4 frags of 16x16), mfma_f32_16x16x32_bf16.

// GEMM1: hT[(e*O+o)][(b*S+s)] = sum_d WcT[(e,o)][d] * xb[(b,s)][d] + bc[e,o]
// M=4096 (blockIdx.x*128), N=8192 (blockIdx.y*128), K=512
__global__ __launch_bounds__(256) void k_gemm1(const ushort_t* __restrict__ WcT,
                                               const ushort_t* __restrict__ xb,
                                               const float* __restrict__ bc,
                                               ushort_t* __restrict__ hT) {
  __shared__ __attribute__((aligned(16))) ushort_t lA[128 * 64];
  __shared__ __attribute__((aligned(16))) ushort_t lB[128 * 64];
  const int tid = threadIdx.x;
  const int m0 = blockIdx.x * 128, n0 = blockIdx.y * 128;
  const int tr = tid >> 3, tc = (tid & 7) * 8;
  const int lane = tid & 63, wid = tid >> 6;
  const int wr = wid >> 1, wc = wid & 1;
  const int lr = lane & 15, lk = (lane >> 4) * 8, lq = lane >> 4;

  f32x4 acc[4][4];
#pragma unroll
  for (int i = 0; i < 4; ++i)
#pragma unroll
    for (int j = 0; j < 4; ++j) acc[i][j] = (f32x4){0.f, 0.f, 0.f, 0.f};

  const ushort_t* gA = WcT + (size_t)(m0 + tr) * D_ + tc;
  const ushort_t* gB = xb + (size_t)(n0 + tr) * D_ + tc;

  for (int kk = 0; kk < 8; ++kk) {
    const int k0 = kk * 64;
    __syncthreads();
#pragma unroll
    for (int i = 0; i < 4; ++i) {
      gld_lds16(gA + (size_t)(32 * i) * D_ + k0, lA + tid * 8 + i * 2048);
      gld_lds16(gB + (size_t)(32 * i) * D_ + k0, lB + tid * 8 + i * 2048);
    }
    asm volatile("s_waitcnt vmcnt(0)" ::: "memory");
    __syncthreads();
    const ushort_t* pA = lA + (wr * 64 + lr) * 64 + lk;
    const ushort_t* pB = lB + (wc * 64 + lr) * 64 + lk;
#pragma unroll
    for (int ks = 0; ks < 2; ++ks) {
      short8 av[4], bv[4];
#pragma unroll
      for (int mi = 0; mi < 4; ++mi) av[mi] = *(const short8*)(pA + mi * 16 * 64 + ks * 32);
#pragma unroll
      for (int ni = 0; ni < 4; ++ni) bv[ni] = *(const short8*)(pB + ni * 16 * 64 + ks * 32);
#pragma unroll
      for (int mi = 0; mi < 4; ++mi)
#pragma unroll
        for (int ni = 0; ni < 4; ++ni)
          acc[mi][ni] = __builtin_amdgcn_mfma_f32_16x16x32_bf16(av[mi], bv[ni], acc[mi][ni], 0, 0, 0);
    }
  }

#pragma unroll
  for (int mi = 0; mi < 4; ++mi) {
    const int m_g = m0 + wr * 64 + mi * 16 + lq * 4;
#pragma unroll
    for (int ni = 0; ni < 4; ++ni) {
      const int n_g = n0 + wc * 64 + ni * 16 + lr;
      f32x4 v = acc[mi][ni];
#pragma unroll
      for (int r = 0; r < 4; ++r)
        hT[(size_t)(m_g + r) * (B_ * S_) + n_g] = f2bf(v[r] + bc[m_g + r]);
    }
  }
}

// GEMM2: out[b][s][o] = relu( sum_{e,t} Ahat[b,e,s,t] * hT[(e,o)][(b,t)] )
// grid: (o-tiles=4, s-tiles=4, b=16); K = E*S = 4096 (e-major, 64-chunks of t)
__global__ __launch_bounds__(256) void k_gemm2(const ushort_t* __restrict__ Ahat,
                                               const ushort_t* __restrict__ hT,
                                               float* __restrict__ out) {
  __shared__ __attribute__((aligned(16))) ushort_t lA[128 * 64];
  __shared__ __attribute__((aligned(16))) ushort_t lB[128 * 64];
  const int tid = threadIdx.x;
  const int o0 = blockIdx.x * 128, s0 = blockIdx.y * 128, b = blockIdx.z;
  const int tr = tid >> 3, tc = (tid & 7) * 8;
  const int lane = tid & 63, wid = tid >> 6;
  const int wr = wid >> 1, wc = wid & 1;
  const int lr = lane & 15, lk = (lane >> 4) * 8, lq = lane >> 4;

  f32x4 acc[4][4];
#pragma unroll
  for (int i = 0; i < 4; ++i)
#pragma unroll
    for (int j = 0; j < 4; ++j) acc[i][j] = (f32x4){0.f, 0.f, 0.f, 0.f};

  for (int kk = 0; kk < 64; ++kk) {
    const int e = kk >> 3, t0 = (kk & 7) * 64;
    __syncthreads();
    const ushort_t* gA = Ahat + ((size_t)((b * E_ + e) * S_ + s0 + tr)) * S_ + t0 + tc;
    const ushort_t* gB = hT + ((size_t)(e * O_ + o0 + tr)) * (B_ * S_) + b * S_ + t0 + tc;
#pragma unroll
    for (int i = 0; i < 4; ++i) {
      gld_lds16(gA + (size_t)(32 * i) * S_, lA + tid * 8 + i * 2048);
      gld_lds16(gB + (size_t)(32 * i) * (B_ * S_), lB + tid * 8 + i * 2048);
    }
    asm volatile("s_waitcnt vmcnt(0)" ::: "memory");
    __syncthreads();
    const ushort_t* pA = lA + (wr * 64 + lr) * 64 + lk;  // rows = s
    const ushort_t* pB = lB + (wc * 64 + lr) * 64 + lk;  // rows = o
#pragma unroll
    for (int ks = 0; ks < 2; ++ks) {
      short8 av[4], bv[4];
#pragma unroll
      for (int mi = 0; mi < 4; ++mi) av[mi] = *(const short8*)(pA + mi * 16 * 64 + ks * 32);
#pragma unroll
      for (int ni = 0; ni < 4; ++ni) bv[ni] = *(const short8*)(pB + ni * 16 * 64 + ks * 32);
#pragma unroll
      for (int mi = 0; mi < 4; ++mi)
#pragma unroll
        for (int ni = 0; ni < 4; ++ni)
          acc[mi][ni] = __builtin_amdgcn_mfma_f32_16x16x32_bf16(av[mi], bv[ni], acc[mi][ni], 0, 0, 0);
    }
  }

#pragma unroll
  for (int mi = 0; mi < 4; ++mi) {
    const int s_g = s0 + wr * 64 + mi * 16 + lq * 4;
#pragma unroll
    for (int ni = 0; ni < 4; ++ni) {
      const int o_g = o0 + wc * 64 + ni * 16 + lr;
      f32x4 v = acc[mi][ni];
#pragma unroll
      for (int r = 0; r < 4; ++r)
        out[((size_t)b * S_ + s_g + r) * O_ + o_g] = fmaxf(v[r], 0.f);
    }
  }
}

// ---------------- launch ----------------

extern "C" void kernel_launch(void* const* d_in, const int* in_sizes, int n_in,
                              void* d_out, int out_size, void* d_ws, size_t ws_size,
                              hipStream_t stream) {
  const float* x   = (const float*)d_in[0];  // (B,S,D)
  const float* adj = (const float*)d_in[1];  // (B,E,S,S)
  const float* Wg  = (const float*)d_in[2];  // (E,D)
  const float* bg  = (const float*)d_in[3];  // (E,)
  const float* Wc  = (const float*)d_in[4];  // (E,D,O)
  const float* bc  = (const float*)d_in[5];  // (E,O)
  float* out = (float*)d_out;                // (B,S,O)

  // workspace carve (all 16B-aligned). Total ~147.5 MB.
  char* ws = (char*)d_ws;
  float* gates  = (float*)ws;    ws += (size_t)B_ * E_ * S_ * 4;        //  0.26 MB
  ushort_t* xb  = (ushort_t*)ws; ws += (size_t)B_ * S_ * D_ * 2;        //  8.4  MB
  ushort_t* WcT = (ushort_t*)ws; ws += (size_t)E_ * O_ * D_ * 2;        //  4.2  MB
  ushort_t* hT  = (ushort_t*)ws; ws += (size_t)E_ * O_ * B_ * S_ * 2;   // 67.1  MB
  ushort_t* Ahat = (ushort_t*)ws;                                       // 67.1  MB

  k_cvt_x<<<dim3((B_ * S_ * D_) / (256 * 8)), dim3(256), 0, stream>>>(x, xb);
  k_wcT<<<dim3(O_ / 64, D_ / 64, E_), dim3(256), 0, stream>>>(Wc, WcT);
  k_gates<<<dim3((B_ * S_) / 4), dim3(256), 0, stream>>>(x, Wg, bg, gates);
  k_ahat<<<dim3((size_t)(B_ * E_ * S_) * S_ / (256 * 8)), dim3(256), 0, stream>>>(adj, gates, Ahat);
  k_gemm1<<<dim3((E_ * O_) / 128, (B_ * S_) / 128), dim3(256), 0, stream>>>(WcT, xb, bc, hT);
  k_gemm2<<<dim3(O_ / 128, S_ / 128, B_), dim3(256), 0, stream>>>(Ahat, hT, out);
}